// Round 10
// baseline (640.346 us; speedup 1.0000x reference)
//
#include <hip/hip_runtime.h>
#include <stdint.h>

#define NHEADS 16
#define DHEAD 64
#define SEQ 2048
#define BATCH 2
#define NINF 1024
#define NOUTF 1024
#define N3 3072
#define MTOT 4096  // BATCH*SEQ
#define MB (1u << 20)

typedef unsigned short US;
typedef __attribute__((ext_vector_type(8))) short short8;
typedef __attribute__((ext_vector_type(4))) short short4v;
typedef __attribute__((ext_vector_type(4))) float f32x4;

__device__ inline US f2bf(float f) {
  union { float f; unsigned u; } v; v.f = f;
  unsigned r = v.u + 0x7fffu + ((v.u >> 16) & 1u);
  return (US)(r >> 16);
}

__device__ inline f32x4 mfma16(short8 a, short8 b, f32x4 c) {
  return __builtin_amdgcn_mfma_f32_16x16x32_bf16(a, b, c, 0, 0, 0);
}

__device__ inline f32x4 mfma16k16(short4v a, short4v b, f32x4 c) {
  return __builtin_amdgcn_mfma_f32_16x16x16bf16_1k(a, b, c, 0, 0, 0);
}

__device__ inline void async16(const US* g, US* l) {
  __builtin_amdgcn_global_load_lds(
      (const __attribute__((address_space(1))) unsigned int*)g,
      (__attribute__((address_space(3))) unsigned int*)l, 16, 0, 0);
}

// grid barrier: single monotone counter at *cnt (zeroed per run by a captured
// memset). All 1024 blocks are co-resident BY CONSTRUCTION:
// __launch_bounds__(256,4) caps VGPR at 128 -> >=4 blocks/CU; LDS 32KB -> 5/CU;
// grid == 4*256 exactly. threshold = phase*1024. __threadfence() is agent
// scope on gfx950 (L2 writeback/invalidate) -> cross-XCD visibility (G16).
__device__ inline void gbar(unsigned* cnt, unsigned th) {
  __syncthreads();
  if (threadIdx.x == 0) {
    __threadfence();                     // release: drain + wb L2
    atomicAdd(cnt, 1u);                  // device-scope by default
    while (__hip_atomic_load(cnt, __ATOMIC_RELAXED, __HIP_MEMORY_SCOPE_AGENT) < th)
      __builtin_amdgcn_s_sleep(2);
    __threadfence();                     // acquire: inv L2
  }
  __syncthreads();
}

// ---------------- one fused kernel: pre -> qkv -> vtrans -> attn -> out ----
// v15: per-dispatch sums ~118us vs 181-183 wall -> ~60us of inter-dispatch
// gap (~12us x 5). Fuse everything; kernel interiors are the PROVEN-BEST
// forms verbatim (qkv v13 BK=32 uniform-swap, attn v8, out 64x64 for full
// residency). 4 grid barriers replace 4 dispatch boundaries.
__global__ __launch_bounds__(256, 4) void k_fused(
    const float* __restrict__ y, const float* __restrict__ Wqkv,
    const float* __restrict__ Wff, const float* __restrict__ bff,
    float* __restrict__ out, char* __restrict__ ws) {
  __shared__ __align__(16) char smem[32768];
  US* ybf   = (US*)(ws);                 // [0,8M)   y bf16; dead after qkv
  US* ctx   = (US*)(ws);                 // [0,8M)   reuse for ctx (attn out)
  US* wqkvt = (US*)(ws + 8 * MB);        // [8,14M)
  US* wfft  = (US*)(ws + 14 * MB);       // [14,16M)
  US* qbuf  = (US*)(ws + 16 * MB);       // [16,24M)
  US* kbuf  = (US*)(ws + 24 * MB);       // [24,32M)
  US* vbuf  = (US*)(ws + 32 * MB);       // [32,40M) dead after vtrans
  US* vtbuf = (US*)(ws + 40 * MB);       // [40,48M)
  unsigned* cnt = (unsigned*)out;        // barrier counter; out[0] written only
                                         // in the final phase (after last gbar)
  int bl = blockIdx.x;                   // 1024 blocks
  int tid = threadIdx.x;
  int wave = tid >> 6, lane = tid & 63, lm = lane & 15, lk = lane >> 4;

  // ================= phase 1: y convert + weight transpose =================
  {
#pragma unroll
    for (int p = 0; p < 4; ++p) {
      int i = (p * 1024 + bl) * 256 + tid;      // exactly 1M float4
      float4 v = ((const float4*)y)[i];
      ushort4 o;
      o.x = f2bf(v.x); o.y = f2bf(v.y); o.z = f2bf(v.z); o.w = f2bf(v.w);
      ((ushort4*)ybf)[i] = o;
    }
    float (*tile)[33] = (float(*)[33])smem;
    int tx = tid & 31, ty = tid >> 5;
    for (int q = 0; q < 4; ++q) {
      int t = bl * 4 + q;                       // 0..4095 tiles
      int bxi = t & 127, byi = t >> 7;
      const float* src; US* dst; int C;
      if (bxi < 96) { src = Wqkv; dst = wqkvt; C = N3; }
      else          { src = Wff;  dst = wfft;  C = NOUTF; bxi -= 96; }
      int bx = bxi * 32, by = byi * 32;
      for (int i2 = 0; i2 < 32; i2 += 8)
        tile[ty + i2][tx] = src[(size_t)(by + ty + i2) * C + bx + tx];
      __syncthreads();
      for (int i2 = 0; i2 < 32; i2 += 8)
        dst[(size_t)(bx + ty + i2) * 1024 + by + tx] = f2bf(tile[tx][ty + i2]);
      __syncthreads();
    }
  }
  gbar(cnt, 1024u);

  // ================= phase 2: qkv GEMM (v13 proven: BK=32, uniform swap) ====
  if (bl < 768) {
    US* As = (US*)smem;                  // 128x32
    US* Bs = (US*)(smem + 8192);
    int wm = wave >> 1, wn = wave & 1;
    int mbase = (bl / 24) * 128, nbase = (bl % 24) * 128;

    f32x4 acc[4][4];
#pragma unroll
    for (int i = 0; i < 4; ++i)
#pragma unroll
      for (int j = 0; j < 4; ++j) acc[i][j] = (f32x4){0.f, 0.f, 0.f, 0.f};

    const US* ga = ybf + (size_t)(mbase + (tid >> 2)) * NINF + (tid & 3) * 8;
    const US* gb = wqkvt + (size_t)(nbase + (tid >> 2)) * NINF + (tid & 3) * 8;
    US* la = As + tid * 8;
    US* lb = Bs + tid * 8;

    for (int kt = 0; kt < 32; ++kt) {
      int ko = kt * 32;
      async16(ga + ko, la);
      async16(ga + ko + (size_t)64 * NINF, la + 2048);
      async16(gb + ko, lb);
      async16(gb + ko + (size_t)64 * NINF, lb + 2048);
      __syncthreads();
      short8 a[4], b[4];
#pragma unroll
      for (int i = 0; i < 4; ++i)
        a[i] = *(const short8*)(As + (wm * 64 + i * 16 + lm) * 32 + lk * 8);
#pragma unroll
      for (int j = 0; j < 4; ++j)
        b[j] = *(const short8*)(Bs + (wn * 64 + j * 16 + lm) * 32 + lk * 8);
      // swapped: lane holds C[m=..+i*16+lm][n=..+j*16+lk*4+r]
#pragma unroll
      for (int i = 0; i < 4; ++i)
#pragma unroll
        for (int j = 0; j < 4; ++j) acc[i][j] = mfma16(b[j], a[i], acc[i][j]);
      __syncthreads();
    }

    int which = nbase >> 10;  // 0=q 1=k 2=v (uniform per block)
    US* dsts = (which == 0) ? qbuf : (which == 1) ? kbuf : vbuf;
    float sc = (which == 0) ? 0.18033688011112042f : 1.f;  // log2(e)/8 in Q
    int hh = ((nbase + wn * 64) & 1023) >> 6;
#pragma unroll
    for (int i = 0; i < 4; ++i) {
      int row = mbase + wm * 64 + i * 16 + lm;
      int bh = (row >> 11) * NHEADS + hh;
      int s = row & (SEQ - 1);
      US* base = dsts + ((size_t)bh * SEQ + s) * DHEAD;
#pragma unroll
      for (int j = 0; j < 4; ++j) {
        int d0 = j * 16 + lk * 4;
        uint32_t lo = (uint32_t)f2bf(acc[i][j][0] * sc) | ((uint32_t)f2bf(acc[i][j][1] * sc) << 16);
        uint32_t hi = (uint32_t)f2bf(acc[i][j][2] * sc) | ((uint32_t)f2bf(acc[i][j][3] * sc) << 16);
        uint2 pv; pv.x = lo; pv.y = hi;
        *(uint2*)(base + d0) = pv;
      }
    }
  }
  gbar(cnt, 2048u);

  // ================= phase 3: V transpose =================
  {
    US (*tile)[33] = (US(*)[33])smem;
    int tx = tid & 31, ty = tid >> 5;
#pragma unroll
    for (int q = 0; q < 4; ++q) {
      int t = q * 1024 + bl;               // 0..4095 tiles
      int bh = t & 31;
      int sy = (t >> 5) & 63;
      int dx = t >> 11;                    // 0..1
      const US* s0 = vbuf + (size_t)bh * SEQ * DHEAD;
      US* d0 = vtbuf + (size_t)bh * DHEAD * SEQ;
      int bx = dx * 32, by = sy * 32;
      for (int i2 = 0; i2 < 32; i2 += 8)
        tile[ty + i2][tx] = s0[(size_t)(by + ty + i2) * DHEAD + bx + tx];
      __syncthreads();
      for (int i2 = 0; i2 < 32; i2 += 8)
        d0[(size_t)(bx + ty + i2) * SEQ + by + tx] = tile[tx][ty + i2];
      __syncthreads();
    }
  }
  gbar(cnt, 3072u);

  // ================= phase 4: attention (v8 proven, 45.7us) =================
  {
    US* KsP = (US*)smem;                   // [2][4096]
    US* VsP = (US*)(smem + 16384);         // [2][4096]
    int w = wave;
    int xcd = bl & 7, g = bl >> 3;
    int bh = (g & 3) * 8 + xcd;
    int q4 = g >> 2;
    int rnd = q4 >> 3, qq = q4 & 7;
    int s = (rnd == 0) ? 31 - qq : (rnd == 1) ? qq : (rnd == 2) ? 23 - qq : 8 + qq;
    int qb = s * 64 + w * 16;
    int nt = s + 1;

    const US* kbase = kbuf + (size_t)bh * SEQ * DHEAD;
    const US* vtb = vtbuf + (size_t)bh * DHEAD * SEQ;
    const US* qr = qbuf + ((size_t)bh * SEQ + qb + lm) * DHEAD + lk * 8;
    short8 qf0 = *(const short8*)(qr);
    short8 qf1 = *(const short8*)(qr + 32);

    int swz = ((lane & 7) ^ (lane >> 3)) * 8;
    const US* gsrc[4];
    US* ldst[4];
    int step[4];
#pragma unroll
    for (int j = 0; j < 4; ++j) {
      int u = w + 4 * j;
      if (u < 8) {
        gsrc[j] = kbase + (size_t)(u * 8 + (lane >> 3)) * DHEAD + swz;
        ldst[j] = KsP + u * 512 + lane * 8;
        step[j] = 64 * DHEAD;
      } else {
        int i = u - 8;
        gsrc[j] = vtb + (size_t)(i * 8 + (lane >> 3)) * SEQ + swz;
        ldst[j] = VsP + i * 512 + lane * 8;
        step[j] = 64;
      }
    }

    int xorv = lm & 7;
    int ck0 = ((lk) ^ xorv) * 16;
    int ck1 = ((4 + lk) ^ xorv) * 16;
    int cv[4];
#pragma unroll
    for (int kg = 0; kg < 4; ++kg)
      cv[kg] = (((kg * 2 + (lk >> 1)) ^ xorv) * 16) + (lk & 1) * 8;

    f32x4 o[4];
#pragma unroll
    for (int dg = 0; dg < 4; ++dg) o[dg] = (f32x4){0.f, 0.f, 0.f, 0.f};
    f32x4 lacc = (f32x4){0.f, 0.f, 0.f, 0.f};
    const short4v kones = {(short)0x3F80, (short)0x3F80, (short)0x3F80, (short)0x3F80};

    auto body = [&](const char* Kc, const char* Vc, int kg, bool dm) {
      const char* kr = Kc + (kg * 16 + lm) * 128;
      short8 ka0 = *(const short8*)(kr + ck0);
      short8 ka1 = *(const short8*)(kr + ck1);
      f32x4 st = (f32x4){0.f, 0.f, 0.f, 0.f};
      st = mfma16(ka0, qf0, st);
      st = mfma16(ka1, qf1, st);
      uint32_t ue[4];
#pragma unroll
      for (int r = 0; r < 4; ++r) {
        float v = st[r];
        if (dm && (lk * 4 + r > lm)) v = -INFINITY;
        union { float f; uint32_t u; } cv2;
        cv2.f = exp2f(v);
        ue[r] = cv2.u + 0x8000u;
      }
      union { short4v s4; uint32_t u[2]; } pk;
      pk.u[0] = __builtin_amdgcn_perm(ue[1], ue[0], 0x07060302u);
      pk.u[1] = __builtin_amdgcn_perm(ue[3], ue[2], 0x07060302u);
      lacc = mfma16k16(kones, pk.s4, lacc);
      const char* vr = Vc + lm * 128 + cv[kg];
#pragma unroll
      for (int dg = 0; dg < 4; ++dg) {
        short4v va = *(const short4v*)(vr + dg * 2048);
        o[dg] = mfma16k16(va, pk.s4, o[dg]);
      }
    };

#pragma unroll
    for (int j = 0; j < 4; ++j) { async16(gsrc[j], ldst[j]); gsrc[j] += step[j]; }
    if (nt > 1) {
#pragma unroll
      for (int j = 0; j < 4; ++j) { async16(gsrc[j], ldst[j] + 4096); gsrc[j] += step[j]; }
    }

    for (int t = 0; t < nt; ++t) {
      if (t + 1 < nt) asm volatile("s_waitcnt vmcnt(4)" ::: "memory");
      else            asm volatile("s_waitcnt vmcnt(0)" ::: "memory");
      __builtin_amdgcn_s_barrier();
      asm volatile("" ::: "memory");
      const char* Kc = (const char*)KsP + (t & 1) * 8192;
      const char* Vc = (const char*)VsP + (t & 1) * 8192;
      if (t < s) {
#pragma unroll
        for (int kg = 0; kg < 4; ++kg) body(Kc, Vc, kg, false);
      } else {
        for (int kg = 0; kg < w; ++kg) body(Kc, Vc, kg, false);
        body(Kc, Vc, w, true);
      }
      asm volatile("" ::: "memory");
      __builtin_amdgcn_s_barrier();
      asm volatile("" ::: "memory");
      if (t + 2 < nt) {
#pragma unroll
        for (int j = 0; j < 4; ++j) {
          async16(gsrc[j], ldst[j] + (t & 1) * 4096);
          gsrc[j] += step[j];
        }
      }
    }

    float inv = 1.f / lacc[0];
    US* crow = ctx + ((size_t)(bh >> 4) * SEQ + qb + lm) * NOUTF + (bh & 15) * DHEAD;
#pragma unroll
    for (int dg = 0; dg < 4; ++dg) {
      union { short4v s4; uint32_t u[2]; } pk;
      pk.u[0] = (uint32_t)f2bf(o[dg][0] * inv) | ((uint32_t)f2bf(o[dg][1] * inv) << 16);
      pk.u[1] = (uint32_t)f2bf(o[dg][2] * inv) | ((uint32_t)f2bf(o[dg][3] * inv) << 16);
      *(short4v*)(crow + dg * 16 + lk * 4) = pk.s4;
    }
  }
  gbar(cnt, 4096u);

  // ================= phase 5: out GEMM (64x64, full residency) =================
  {
    US* As = (US*)smem;                   // 64x32
    US* Bs = (US*)(smem + 4096);
    int wm = wave >> 1, wn = wave & 1;
    int mbase = (bl >> 4) * 64, nbase = (bl & 15) * 64;

    f32x4 acc[2][2];
#pragma unroll
    for (int i = 0; i < 2; ++i)
#pragma unroll
      for (int j = 0; j < 2; ++j) acc[i][j] = (f32x4){0.f, 0.f, 0.f, 0.f};

    const US* ga = ctx + (size_t)(mbase + (tid >> 2)) * NOUTF + (tid & 3) * 8;
    const US* gb = wfft + (size_t)(nbase + (tid >> 2)) * NOUTF + (tid & 3) * 8;
    US* la = As + tid * 8;
    US* lb = Bs + tid * 8;

    for (int kt = 0; kt < 32; ++kt) {
      int ko = kt * 32;
      async16(ga + ko, la);
      async16(gb + ko, lb);
      __syncthreads();
      short8 a[2], b[2];
#pragma unroll
      for (int i = 0; i < 2; ++i)
        a[i] = *(const short8*)(As + (wm * 32 + i * 16 + lm) * 32 + lk * 8);
#pragma unroll
      for (int j = 0; j < 2; ++j)
        b[j] = *(const short8*)(Bs + (wn * 32 + j * 16 + lm) * 32 + lk * 8);
      // swapped: lane holds out[m=..+i*16+lm][n=..+j*16+lk*4+r]
#pragma unroll
      for (int i = 0; i < 2; ++i)
#pragma unroll
        for (int j = 0; j < 2; ++j) acc[i][j] = mfma16(b[j], a[i], acc[i][j]);
      __syncthreads();
    }

#pragma unroll
    for (int j = 0; j < 2; ++j) {
      int n0 = nbase + wn * 32 + j * 16 + lk * 4;
      float4 bv = *(const float4*)(bff + n0);
#pragma unroll
      for (int i = 0; i < 2; ++i) {
        int row = mbase + wm * 32 + i * 16 + lm;
        float4 ov;
        ov.x = acc[i][j][0] + bv.x;
        ov.y = acc[i][j][1] + bv.y;
        ov.z = acc[i][j][2] + bv.z;
        ov.w = acc[i][j][3] + bv.w;
        *(float4*)(out + (size_t)row * NOUTF + n0) = ov;
      }
    }
  }
}

extern "C" void kernel_launch(void* const* d_in, const int* in_sizes, int n_in,
                              void* d_out, int out_size, void* d_ws, size_t ws_size,
                              hipStream_t stream) {
  const float* y    = (const float*)d_in[0];
  const float* Wqkv = (const float*)d_in[1];
  const float* Wff  = (const float*)d_in[2];
  const float* bff  = (const float*)d_in[3];
  float* out = (float*)d_out;

  // zero the grid-barrier counter (out[0]; overwritten by the final phase)
  hipMemsetAsync(d_out, 0, 4, stream);
  k_fused<<<dim3(1024), 256, 0, stream>>>(y, Wqkv, Wff, bff, out, (char*)d_ws);
}

// Round 14
// 390.603 us; speedup vs baseline: 1.6394x; 1.6394x over previous
//
#include <hip/hip_runtime.h>
#include <stdint.h>

#define NHEADS 16
#define DHEAD 64
#define SEQ 2048
#define BATCH 2
#define NINF 1024
#define NOUTF 1024
#define N3 3072
#define MTOT 4096  // BATCH*SEQ
#define MB (1u << 20)

typedef unsigned short US;
typedef __attribute__((ext_vector_type(8))) short short8;
typedef __attribute__((ext_vector_type(4))) short short4v;
typedef __attribute__((ext_vector_type(4))) float f32x4;

__device__ inline US f2bf(float f) {
  union { float f; unsigned u; } v; v.f = f;
  unsigned r = v.u + 0x7fffu + ((v.u >> 16) & 1u);
  return (US)(r >> 16);
}

__device__ inline f32x4 mfma16(short8 a, short8 b, f32x4 c) {
  return __builtin_amdgcn_mfma_f32_16x16x32_bf16(a, b, c, 0, 0, 0);
}

__device__ inline f32x4 mfma16k16(short4v a, short4v b, f32x4 c) {
  return __builtin_amdgcn_mfma_f32_16x16x16bf16_1k(a, b, c, 0, 0, 0);
}

__device__ inline void async16(const US* g, US* l) {
  __builtin_amdgcn_global_load_lds(
      (const __attribute__((address_space(1))) unsigned int*)g,
      (__attribute__((address_space(3))) unsigned int*)l, 16, 0, 0);
}

// ---- grid barrier v3: EPOCH-based, monotone counters, zero resets ---------
// v15 (all-poll-one-line): correct but poll flood -> 3.3x stretch.
// v16/v17 (leader/release + ack/reset): reset race across graph replays is a
// latent deadlock class (any interrupted replay corrupts state forever), and
// the 1023-ack collection is itself an all-to-one RMW flood.
// v18: counters only ever INCREASE. At entry each block reads rb=g_rel[0];
// rb is stable (g_rel advances only after all 1024 blocks have read it and
// arrived at barrier 0; replays are stream-serialized). Epoch N: rb=4N and
// g_cnt[b]=1024N=rb*256. Leader waits (g_cnt[b]-rb*256)>=1024 (single
// poller), releases g_rel=rb+b+1; others poll the read-only release line at
// s_sleep(64). Wraparound-safe via unsigned subtraction. No epilogue.
// (Resubmitted unchanged: round-13 failure was GPUAcquisitionTimeout --
// the kernel never ran.)
__device__ __attribute__((aligned(256))) unsigned g_cnt[4 * 64];  // arrival counters
__device__ __attribute__((aligned(256))) unsigned g_rel[64];      // release word

__device__ inline void gbar(int b, int bl, unsigned rb) {
  __syncthreads();
  if (threadIdx.x == 0) {
    __threadfence();   // release: make this block's phase writes visible
    atomicAdd(&g_cnt[b * 64], 1u);
    if (bl == 0) {
      while ((unsigned)(__hip_atomic_load(&g_cnt[b * 64], __ATOMIC_RELAXED,
                                          __HIP_MEMORY_SCOPE_AGENT) - rb * 256u) < 1024u)
        __builtin_amdgcn_s_sleep(8);
      __hip_atomic_store(&g_rel[0], rb + (unsigned)(b + 1), __ATOMIC_RELAXED,
                         __HIP_MEMORY_SCOPE_AGENT);
    } else {
      while ((unsigned)(__hip_atomic_load(&g_rel[0], __ATOMIC_RELAXED,
                                          __HIP_MEMORY_SCOPE_AGENT) - rb) < (unsigned)(b + 1))
        __builtin_amdgcn_s_sleep(64);
    }
    __threadfence();   // acquire: invalidate stale caches before reading
  }
  __syncthreads();
}

// ---------------- one fused kernel: pre -> qkv -> vtrans -> attn -> out ----
// Phase bodies: proven-best standalone forms verbatim (qkv v13 BK=32 uniform
// swap, attn v8 45.7us, out ORIGINAL 128x64 full-256-thread B staging).
// 4 grid barriers replace 4 dispatch boundaries (r9 accounting: dispatch sum
// ~118us vs wall 181us -> ~60us of gaps). Fused dataflow correctness proven
// in v15 (absmax 0.015625 over all replays).
__global__ __launch_bounds__(256, 4) void k_fused(
    const float* __restrict__ y, const float* __restrict__ Wqkv,
    const float* __restrict__ Wff, const float* __restrict__ bff,
    float* __restrict__ out, char* __restrict__ ws) {
  __shared__ __align__(16) char smem[32768];
  US* ybf   = (US*)(ws);                 // [0,8M)   y bf16; dead after qkv
  US* ctx   = (US*)(ws);                 // [0,8M)   reuse for ctx (attn out)
  US* wqkvt = (US*)(ws + 8 * MB);        // [8,14M)
  US* wfft  = (US*)(ws + 14 * MB);       // [14,16M)
  US* qbuf  = (US*)(ws + 16 * MB);       // [16,24M)
  US* kbuf  = (US*)(ws + 24 * MB);       // [24,32M)
  US* vbuf  = (US*)(ws + 32 * MB);       // [32,40M) dead after vtrans
  US* vtbuf = (US*)(ws + 40 * MB);       // [40,48M)
  int bl = blockIdx.x;                   // 1024 blocks
  int tid = threadIdx.x;
  int wave = tid >> 6, lane = tid & 63, lm = lane & 15, lk = lane >> 4;

  // entry epoch read (stable: see gbar comment). Only tid 0's value is used.
  unsigned rb = 0;
  if (tid == 0)
    rb = __hip_atomic_load(&g_rel[0], __ATOMIC_RELAXED, __HIP_MEMORY_SCOPE_AGENT);

  // ================= phase 1: y convert + weight transpose =================
  {
#pragma unroll
    for (int p = 0; p < 4; ++p) {
      int i = (p * 1024 + bl) * 256 + tid;      // exactly 1M float4
      float4 v = ((const float4*)y)[i];
      ushort4 o;
      o.x = f2bf(v.x); o.y = f2bf(v.y); o.z = f2bf(v.z); o.w = f2bf(v.w);
      ((ushort4*)ybf)[i] = o;
    }
    float (*tile)[33] = (float(*)[33])smem;
    int tx = tid & 31, ty = tid >> 5;
    for (int q = 0; q < 4; ++q) {
      int t = bl * 4 + q;                       // 0..4095 tiles
      int bxi = t & 127, byi = t >> 7;
      const float* src; US* dst; int C;
      if (bxi < 96) { src = Wqkv; dst = wqkvt; C = N3; }
      else          { src = Wff;  dst = wfft;  C = NOUTF; bxi -= 96; }
      int bx = bxi * 32, by = byi * 32;
      for (int i2 = 0; i2 < 32; i2 += 8)
        tile[ty + i2][tx] = src[(size_t)(by + ty + i2) * C + bx + tx];
      __syncthreads();
      for (int i2 = 0; i2 < 32; i2 += 8)
        dst[(size_t)(bx + ty + i2) * 1024 + by + tx] = f2bf(tile[tx][ty + i2]);
      __syncthreads();
    }
  }
  gbar(0, bl, rb);

  // ================= phase 2: qkv GEMM (v13 proven: BK=32, uniform swap) ====
  if (bl < 768) {
    US* As = (US*)smem;                  // 128x32
    US* Bs = (US*)(smem + 8192);
    int wm = wave >> 1, wn = wave & 1;
    int mbase = (bl / 24) * 128, nbase = (bl % 24) * 128;

    f32x4 acc[4][4];
#pragma unroll
    for (int i = 0; i < 4; ++i)
#pragma unroll
      for (int j = 0; j < 4; ++j) acc[i][j] = (f32x4){0.f, 0.f, 0.f, 0.f};

    const US* ga = ybf + (size_t)(mbase + (tid >> 2)) * NINF + (tid & 3) * 8;
    const US* gb = wqkvt + (size_t)(nbase + (tid >> 2)) * NINF + (tid & 3) * 8;
    US* la = As + tid * 8;
    US* lb = Bs + tid * 8;

    for (int kt = 0; kt < 32; ++kt) {
      int ko = kt * 32;
      async16(ga + ko, la);
      async16(ga + ko + (size_t)64 * NINF, la + 2048);
      async16(gb + ko, lb);
      async16(gb + ko + (size_t)64 * NINF, lb + 2048);
      __syncthreads();
      short8 a[4], b[4];
#pragma unroll
      for (int i = 0; i < 4; ++i)
        a[i] = *(const short8*)(As + (wm * 64 + i * 16 + lm) * 32 + lk * 8);
#pragma unroll
      for (int j = 0; j < 4; ++j)
        b[j] = *(const short8*)(Bs + (wn * 64 + j * 16 + lm) * 32 + lk * 8);
      // swapped: lane holds C[m=..+i*16+lm][n=..+j*16+lk*4+r]
#pragma unroll
      for (int i = 0; i < 4; ++i)
#pragma unroll
        for (int j = 0; j < 4; ++j) acc[i][j] = mfma16(b[j], a[i], acc[i][j]);
      __syncthreads();
    }

    int which = nbase >> 10;  // 0=q 1=k 2=v (uniform per block)
    US* dsts = (which == 0) ? qbuf : (which == 1) ? kbuf : vbuf;
    float sc = (which == 0) ? 0.18033688011112042f : 1.f;  // log2(e)/8 in Q
    int hh = ((nbase + wn * 64) & 1023) >> 6;
#pragma unroll
    for (int i = 0; i < 4; ++i) {
      int row = mbase + wm * 64 + i * 16 + lm;
      int bh = (row >> 11) * NHEADS + hh;
      int s = row & (SEQ - 1);
      US* base = dsts + ((size_t)bh * SEQ + s) * DHEAD;
#pragma unroll
      for (int j = 0; j < 4; ++j) {
        int d0 = j * 16 + lk * 4;
        uint32_t lo = (uint32_t)f2bf(acc[i][j][0] * sc) | ((uint32_t)f2bf(acc[i][j][1] * sc) << 16);
        uint32_t hi = (uint32_t)f2bf(acc[i][j][2] * sc) | ((uint32_t)f2bf(acc[i][j][3] * sc) << 16);
        uint2 pv; pv.x = lo; pv.y = hi;
        *(uint2*)(base + d0) = pv;
      }
    }
  }
  gbar(1, bl, rb);

  // ================= phase 3: V transpose =================
  {
    US (*tile)[33] = (US(*)[33])smem;
    int tx = tid & 31, ty = tid >> 5;
#pragma unroll
    for (int q = 0; q < 4; ++q) {
      int t = q * 1024 + bl;               // 0..4095 tiles
      int bh = t & 31;
      int sy = (t >> 5) & 63;
      int dx = t >> 11;                    // 0..1
      const US* s0 = vbuf + (size_t)bh * SEQ * DHEAD;
      US* d0 = vtbuf + (size_t)bh * DHEAD * SEQ;
      int bx = dx * 32, by = sy * 32;
      for (int i2 = 0; i2 < 32; i2 += 8)
        tile[ty + i2][tx] = s0[(size_t)(by + ty + i2) * DHEAD + bx + tx];
      __syncthreads();
      for (int i2 = 0; i2 < 32; i2 += 8)
        d0[(size_t)(bx + ty + i2) * SEQ + by + tx] = tile[tx][ty + i2];
      __syncthreads();
    }
  }
  gbar(2, bl, rb);

  // ================= phase 4: attention (v8 proven, 45.7us) =================
  {
    US* KsP = (US*)smem;                   // [2][4096]
    US* VsP = (US*)(smem + 16384);         // [2][4096]
    int w = wave;
    int xcd = bl & 7, g = bl >> 3;
    int bh = (g & 3) * 8 + xcd;
    int q4 = g >> 2;
    int rnd = q4 >> 3, qq = q4 & 7;
    int s = (rnd == 0) ? 31 - qq : (rnd == 1) ? qq : (rnd == 2) ? 23 - qq : 8 + qq;
    int qb = s * 64 + w * 16;
    int nt = s + 1;

    const US* kbase = kbuf + (size_t)bh * SEQ * DHEAD;
    const US* vtb = vtbuf + (size_t)bh * DHEAD * SEQ;
    const US* qr = qbuf + ((size_t)bh * SEQ + qb + lm) * DHEAD + lk * 8;
    short8 qf0 = *(const short8*)(qr);
    short8 qf1 = *(const short8*)(qr + 32);

    int swz = ((lane & 7) ^ (lane >> 3)) * 8;
    const US* gsrc[4];
    US* ldst[4];
    int step[4];
#pragma unroll
    for (int j = 0; j < 4; ++j) {
      int u = w + 4 * j;
      if (u < 8) {
        gsrc[j] = kbase + (size_t)(u * 8 + (lane >> 3)) * DHEAD + swz;
        ldst[j] = KsP + u * 512 + lane * 8;
        step[j] = 64 * DHEAD;
      } else {
        int i = u - 8;
        gsrc[j] = vtb + (size_t)(i * 8 + (lane >> 3)) * SEQ + swz;
        ldst[j] = VsP + i * 512 + lane * 8;
        step[j] = 64;
      }
    }

    int xorv = lm & 7;
    int ck0 = ((lk) ^ xorv) * 16;
    int ck1 = ((4 + lk) ^ xorv) * 16;
    int cv[4];
#pragma unroll
    for (int kg = 0; kg < 4; ++kg)
      cv[kg] = (((kg * 2 + (lk >> 1)) ^ xorv) * 16) + (lk & 1) * 8;

    f32x4 o[4];
#pragma unroll
    for (int dg = 0; dg < 4; ++dg) o[dg] = (f32x4){0.f, 0.f, 0.f, 0.f};
    f32x4 lacc = (f32x4){0.f, 0.f, 0.f, 0.f};
    const short4v kones = {(short)0x3F80, (short)0x3F80, (short)0x3F80, (short)0x3F80};

    auto body = [&](const char* Kc, const char* Vc, int kg, bool dm) {
      const char* kr = Kc + (kg * 16 + lm) * 128;
      short8 ka0 = *(const short8*)(kr + ck0);
      short8 ka1 = *(const short8*)(kr + ck1);
      f32x4 st = (f32x4){0.f, 0.f, 0.f, 0.f};
      st = mfma16(ka0, qf0, st);
      st = mfma16(ka1, qf1, st);
      uint32_t ue[4];
#pragma unroll
      for (int r = 0; r < 4; ++r) {
        float v = st[r];
        if (dm && (lk * 4 + r > lm)) v = -INFINITY;
        union { float f; uint32_t u; } cv2;
        cv2.f = exp2f(v);
        ue[r] = cv2.u + 0x8000u;
      }
      union { short4v s4; uint32_t u[2]; } pk;
      pk.u[0] = __builtin_amdgcn_perm(ue[1], ue[0], 0x07060302u);
      pk.u[1] = __builtin_amdgcn_perm(ue[3], ue[2], 0x07060302u);
      lacc = mfma16k16(kones, pk.s4, lacc);
      const char* vr = Vc + lm * 128 + cv[kg];
#pragma unroll
      for (int dg = 0; dg < 4; ++dg) {
        short4v va = *(const short4v*)(vr + dg * 2048);
        o[dg] = mfma16k16(va, pk.s4, o[dg]);
      }
    };

#pragma unroll
    for (int j = 0; j < 4; ++j) { async16(gsrc[j], ldst[j]); gsrc[j] += step[j]; }
    if (nt > 1) {
#pragma unroll
      for (int j = 0; j < 4; ++j) { async16(gsrc[j], ldst[j] + 4096); gsrc[j] += step[j]; }
    }

    for (int t = 0; t < nt; ++t) {
      if (t + 1 < nt) asm volatile("s_waitcnt vmcnt(4)" ::: "memory");
      else            asm volatile("s_waitcnt vmcnt(0)" ::: "memory");
      __builtin_amdgcn_s_barrier();
      asm volatile("" ::: "memory");
      const char* Kc = (const char*)KsP + (t & 1) * 8192;
      const char* Vc = (const char*)VsP + (t & 1) * 8192;
      if (t < s) {
#pragma unroll
        for (int kg = 0; kg < 4; ++kg) body(Kc, Vc, kg, false);
      } else {
        for (int kg = 0; kg < w; ++kg) body(Kc, Vc, kg, false);
        body(Kc, Vc, w, true);
      }
      asm volatile("" ::: "memory");
      __builtin_amdgcn_s_barrier();
      asm volatile("" ::: "memory");
      if (t + 2 < nt) {
#pragma unroll
        for (int j = 0; j < 4; ++j) {
          async16(gsrc[j], ldst[j] + (t & 1) * 4096);
          gsrc[j] += step[j];
        }
      }
    }

    float inv = 1.f / lacc[0];
    US* crow = ctx + ((size_t)(bh >> 4) * SEQ + qb + lm) * NOUTF + (bh & 15) * DHEAD;
#pragma unroll
    for (int dg = 0; dg < 4; ++dg) {
      union { short4v s4; uint32_t u[2]; } pk;
      pk.u[0] = (uint32_t)f2bf(o[dg][0] * inv) | ((uint32_t)f2bf(o[dg][1] * inv) << 16);
      pk.u[1] = (uint32_t)f2bf(o[dg][2] * inv) | ((uint32_t)f2bf(o[dg][3] * inv) << 16);
      *(short4v*)(crow + dg * 16 + lk * 4) = pk.s4;
    }
  }
  gbar(3, bl, rb);

  // ================= phase 5: out GEMM (original 128x64, 512 blocks) =========
  if (bl < 512) {
    US* As = (US*)smem;                   // 128x32
    US* Bs = (US*)(smem + 8192);          // 64x32
    int mbase = (bl >> 4) * 128, nbase = (bl & 15) * 64;

    f32x4 acc[2][4];
#pragma unroll
    for (int i = 0; i < 2; ++i)
#pragma unroll
      for (int j = 0; j < 4; ++j) acc[i][j] = (f32x4){0.f, 0.f, 0.f, 0.f};

    const US* ga = ctx + (size_t)(mbase + (tid >> 2)) * NOUTF + (tid & 3) * 8;
    const US* gb = wfft + (size_t)(nbase + (tid >> 2)) * NOUTF + (tid & 3) * 8;
    US* la = As + tid * 8;
    US* lb = Bs + tid * 8;

    for (int kt = 0; kt < 32; ++kt) {
      int ko = kt * 32;
      async16(ga + ko, la);
      async16(ga + ko + (size_t)64 * NOUTF, la + 2048);
      async16(gb + ko, lb);   // ALL 256 threads: Bs is 64x32 = 2048 US
      __syncthreads();
      short8 a[2], b[4];
#pragma unroll
      for (int i = 0; i < 2; ++i)
        a[i] = *(const short8*)(As + (wave * 32 + i * 16 + lm) * 32 + lk * 8);
#pragma unroll
      for (int j = 0; j < 4; ++j)
        b[j] = *(const short8*)(Bs + (j * 16 + lm) * 32 + lk * 8);
#pragma unroll
      for (int i = 0; i < 2; ++i)
#pragma unroll
        for (int j = 0; j < 4; ++j) acc[i][j] = mfma16(a[i], b[j], acc[i][j]);
      __syncthreads();
    }

#pragma unroll
    for (int j = 0; j < 4; ++j) {
      int col = nbase + j * 16 + lm;
      float bv = bff[col];
#pragma unroll
      for (int i = 0; i < 2; ++i)
#pragma unroll
        for (int r = 0; r < 4; ++r) {
          int row = mbase + wave * 32 + i * 16 + lk * 4 + r;
          out[(size_t)row * NOUTF + col] = acc[i][j][r] + bv;
        }
    }
  }
}

extern "C" void kernel_launch(void* const* d_in, const int* in_sizes, int n_in,
                              void* d_out, int out_size, void* d_ws, size_t ws_size,
                              hipStream_t stream) {
  const float* y    = (const float*)d_in[0];
  const float* Wqkv = (const float*)d_in[1];
  const float* Wff  = (const float*)d_in[2];
  const float* bff  = (const float*)d_in[3];
  float* out = (float*)d_out;

  k_fused<<<dim3(1024), 256, 0, stream>>>(y, Wqkv, Wff, bff, out, (char*)d_ws);
}

// Round 15
// 184.156 us; speedup vs baseline: 3.4772x; 2.1210x over previous
//
#include <hip/hip_runtime.h>
#include <stdint.h>

#define NHEADS 16
#define DHEAD 64
#define SEQ 2048
#define BATCH 2
#define NINF 1024
#define NOUTF 1024
#define N3 3072
#define MTOT 4096  // BATCH*SEQ

typedef unsigned short US;
typedef __attribute__((ext_vector_type(8))) short short8;
typedef __attribute__((ext_vector_type(4))) short short4v;
typedef __attribute__((ext_vector_type(4))) float f32x4;

__device__ inline US f2bf(float f) {
  union { float f; unsigned u; } v; v.f = f;
  unsigned r = v.u + 0x7fffu + ((v.u >> 16) & 1u);
  return (US)(r >> 16);
}

__device__ inline f32x4 mfma16(short8 a, short8 b, f32x4 c) {
  return __builtin_amdgcn_mfma_f32_16x16x32_bf16(a, b, c, 0, 0, 0);
}

__device__ inline f32x4 mfma16k16(short4v a, short4v b, f32x4 c) {
  return __builtin_amdgcn_mfma_f32_16x16x16bf16_1k(a, b, c, 0, 0, 0);
}

__device__ inline void async16(const US* g, US* l) {
  __builtin_amdgcn_global_load_lds(
      (const __attribute__((address_space(1))) unsigned int*)g,
      (__attribute__((address_space(3))) unsigned int*)l, 16, 0, 0);
}

// ---------------- fused front kernel: convert + wtrans in one dispatch -----
// (r8-proven). blocks [0,4096): y fp32->bf16; [4096,8192): weight transpose.
__global__ __launch_bounds__(256) void k_pre(
    const float* __restrict__ y, US* __restrict__ ybf,
    const float* __restrict__ Wqkv, const float* __restrict__ Wff,
    US* __restrict__ dq, US* __restrict__ df) {
  __shared__ float tile[32][33];
  int bl = blockIdx.x;
  int tid = threadIdx.x;
  if (bl < 4096) {
    int i = bl * 256 + tid;  // i < 1M = MTOT*NINF/4 exactly
    float4 v = ((const float4*)y)[i];
    ushort4 o;
    o.x = f2bf(v.x); o.y = f2bf(v.y); o.z = f2bf(v.z); o.w = f2bf(v.w);
    ((ushort4*)ybf)[i] = o;
  } else {
    int bl2 = bl - 4096;
    int bxi = bl2 & 127, byi = bl2 >> 7;
    const float* src; US* dst; int C;
    if (bxi < 96) { src = Wqkv; dst = dq; C = N3; }
    else          { src = Wff;  dst = df; C = NOUTF; bxi -= 96; }
    int bx = bxi * 32, by = byi * 32;
    int tx = tid & 31, ty = tid >> 5;
    for (int i = 0; i < 32; i += 8)
      tile[ty + i][tx] = src[(size_t)(by + ty + i) * C + bx + tx];
    __syncthreads();
    for (int i = 0; i < 32; i += 8)
      dst[(size_t)(bx + ty + i) * 1024 + by + tx] = f2bf(tile[tx][ty + i]);
  }
}

// per-bh bf16 transpose: vbuf [bh][2048][64] -> vtbuf [bh][64][2048]
__global__ void k_vtrans(const US* __restrict__ src, US* __restrict__ dst) {
  __shared__ US tile[32][33];
  int bh = blockIdx.z;
  int bx = blockIdx.x * 32;  // d
  int by = blockIdx.y * 32;  // s
  int tx = threadIdx.x, ty = threadIdx.y;
  const US* s0 = src + (size_t)bh * SEQ * DHEAD;
  US* d0 = dst + (size_t)bh * DHEAD * SEQ;
  for (int i = 0; i < 32; i += 8)
    tile[ty + i][tx] = s0[(size_t)(by + ty + i) * DHEAD + bx + tx];
  __syncthreads();
  for (int i = 0; i < 32; i += 8)
    d0[(size_t)(bx + ty + i) * SEQ + by + tx] = tile[tx][ty + i];
}

// ---------------- qkv GEMM v13 (proven in r8's 183.0; BK=32, uniform swap) --
// Original single-buffer 2-sync loop (the structure that beat both the
// pipelined v12 and the BK=64 v14). Uniform swapped mfma(b,a) (r walks d),
// vectorized uint2 epilogue into [bh][s][d].
__global__ __launch_bounds__(256) void k_gemm_qkv(
    const US* __restrict__ A,   // [MTOT][NINF]
    const US* __restrict__ Bt,  // [N3][NINF]
    US* __restrict__ qbuf, US* __restrict__ kbuf, US* __restrict__ vbuf) {
  __shared__ US As[128 * 32];
  __shared__ US Bs[128 * 32];
  int tid = threadIdx.x;
  int wave = tid >> 6, lane = tid & 63, lm = lane & 15, lk = lane >> 4;
  int wm = wave >> 1, wn = wave & 1;
  int mbase = blockIdx.y * 128, nbase = blockIdx.x * 128;

  f32x4 acc[4][4];
#pragma unroll
  for (int i = 0; i < 4; ++i)
#pragma unroll
    for (int j = 0; j < 4; ++j) acc[i][j] = (f32x4){0.f, 0.f, 0.f, 0.f};

  const US* ga = A + (size_t)(mbase + (tid >> 2)) * NINF + (tid & 3) * 8;
  const US* gb = Bt + (size_t)(nbase + (tid >> 2)) * NINF + (tid & 3) * 8;
  US* la = As + tid * 8;
  US* lb = Bs + tid * 8;

  for (int kt = 0; kt < NINF / 32; ++kt) {
    int ko = kt * 32;
    async16(ga + ko, la);
    async16(ga + ko + (size_t)64 * NINF, la + 64 * 32);
    async16(gb + ko, lb);
    async16(gb + ko + (size_t)64 * NINF, lb + 64 * 32);
    __syncthreads();
    short8 a[4], b[4];
#pragma unroll
    for (int i = 0; i < 4; ++i)
      a[i] = *(const short8*)(As + (wm * 64 + i * 16 + lm) * 32 + lk * 8);
#pragma unroll
    for (int j = 0; j < 4; ++j)
      b[j] = *(const short8*)(Bs + (wn * 64 + j * 16 + lm) * 32 + lk * 8);
    // swapped: lane holds C[m=mbase+wm*64+i*16+lm][n=nbase+wn*64+j*16+lk*4+r]
#pragma unroll
    for (int i = 0; i < 4; ++i)
#pragma unroll
      for (int j = 0; j < 4; ++j) acc[i][j] = mfma16(b[j], a[i], acc[i][j]);
    __syncthreads();
  }

  int which = nbase >> 10;  // 0=q 1=k 2=v (uniform per block)
  US* dsts = (which == 0) ? qbuf : (which == 1) ? kbuf : vbuf;
  float sc = (which == 0) ? 0.18033688011112042f : 1.f;  // log2(e)/8 folded into Q
  int hh = ((nbase + wn * 64) & 1023) >> 6;  // head of this wave's 64-col block
#pragma unroll
  for (int i = 0; i < 4; ++i) {
    int row = mbase + wm * 64 + i * 16 + lm;
    int bh = (row >> 11) * NHEADS + hh;
    int s = row & (SEQ - 1);
    US* base = dsts + ((size_t)bh * SEQ + s) * DHEAD;
#pragma unroll
    for (int j = 0; j < 4; ++j) {
      int d0 = j * 16 + lk * 4;
      uint32_t lo = (uint32_t)f2bf(acc[i][j][0] * sc) | ((uint32_t)f2bf(acc[i][j][1] * sc) << 16);
      uint32_t hi = (uint32_t)f2bf(acc[i][j][2] * sc) | ((uint32_t)f2bf(acc[i][j][3] * sc) << 16);
      uint2 pv; pv.x = lo; pv.y = hi;
      *(uint2*)(base + d0) = pv;   // 8B contiguous along d
    }
  }
}

// ---------------- attention v8 (proven 45.7-45.9us across 4 rounds) --------
__global__ __launch_bounds__(256) void k_attn(
    const US* __restrict__ qbuf, const US* __restrict__ kbuf,
    const US* __restrict__ vtbuf, US* __restrict__ ctx) {
  __shared__ US Ks[2][64 * 64];
  __shared__ US Vs[2][64 * 64];
  int tid = threadIdx.x;
  int w = tid >> 6, lane = tid & 63;
  int lm = lane & 15, lk = lane >> 4;
  int bl = blockIdx.x;            // 1024 blocks
  int xcd = bl & 7, g = bl >> 3;  // g 0..127
  int bh = (g & 3) * 8 + xcd;     // 4 bh per XCD -> working set ~2MB < 4MB L2
  int q4 = g >> 2;                // 0..31
  int rnd = q4 >> 3, qq = q4 & 7;
  int s = (rnd == 0) ? 31 - qq : (rnd == 1) ? qq : (rnd == 2) ? 23 - qq : 8 + qq;
  int qb = s * 64 + w * 16;
  int nt = s + 1;                 // 64-key tiles (can be 1)

  const US* kbase = kbuf + (size_t)bh * SEQ * DHEAD;
  const US* vtb = vtbuf + (size_t)bh * DHEAD * SEQ;
  const US* qr = qbuf + ((size_t)bh * SEQ + qb + lm) * DHEAD + lk * 8;
  short8 qf0 = *(const short8*)(qr);
  short8 qf1 = *(const short8*)(qr + 32);

  // staging: 16 async16 units (8 K + 8 V), 4 per wave, source-side XOR swizzle
  int swz = ((lane & 7) ^ (lane >> 3)) * 8;
  const US* gsrc[4];
  US* ldst[4];
  int step[4];
#pragma unroll
  for (int j = 0; j < 4; ++j) {
    int u = w + 4 * j;
    if (u < 8) {
      gsrc[j] = kbase + (size_t)(u * 8 + (lane >> 3)) * DHEAD + swz;
      ldst[j] = &Ks[0][0] + u * 512 + lane * 8;
      step[j] = 64 * DHEAD;
    } else {
      int i = u - 8;
      gsrc[j] = vtb + (size_t)(i * 8 + (lane >> 3)) * SEQ + swz;
      ldst[j] = &Vs[0][0] + i * 512 + lane * 8;
      step[j] = 64;
    }
  }

  // fragment-read offsets (bytes), swizzle-corrected
  int xorv = lm & 7;
  int ck0 = ((lk) ^ xorv) * 16;
  int ck1 = ((4 + lk) ^ xorv) * 16;
  int cv[4];
#pragma unroll
  for (int kg = 0; kg < 4; ++kg)
    cv[kg] = (((kg * 2 + (lk >> 1)) ^ xorv) * 16) + (lk & 1) * 8;

  f32x4 o[4];
#pragma unroll
  for (int dg = 0; dg < 4; ++dg) o[dg] = (f32x4){0.f, 0.f, 0.f, 0.f};
  f32x4 lacc = (f32x4){0.f, 0.f, 0.f, 0.f};
  const short4v kones = {(short)0x3F80, (short)0x3F80, (short)0x3F80, (short)0x3F80};

  auto body = [&](const char* Kc, const char* Vc, int kg, bool dm) {
    const char* kr = Kc + (kg * 16 + lm) * 128;
    short8 ka0 = *(const short8*)(kr + ck0);
    short8 ka1 = *(const short8*)(kr + ck1);
    f32x4 st = (f32x4){0.f, 0.f, 0.f, 0.f};
    st = mfma16(ka0, qf0, st);
    st = mfma16(ka1, qf1, st);
    uint32_t ue[4];
#pragma unroll
    for (int r = 0; r < 4; ++r) {
      float v = st[r];                       // already in log2 domain (Q pre-scaled)
      if (dm && (lk * 4 + r > lm)) v = -INFINITY;
      union { float f; uint32_t u; } cv2;
      cv2.f = exp2f(v);
      ue[r] = cv2.u + 0x8000u;               // bf16 bias-round; -inf path -> 0x8000 -> +0
    }
    union { short4v s4; uint32_t u[2]; } pk;
    pk.u[0] = __builtin_amdgcn_perm(ue[1], ue[0], 0x07060302u);
    pk.u[1] = __builtin_amdgcn_perm(ue[3], ue[2], 0x07060302u);
    lacc = mfma16k16(kones, pk.s4, lacc);    // row-sums on the MFMA pipe
    const char* vr = Vc + lm * 128 + cv[kg];
#pragma unroll
    for (int dg = 0; dg < 4; ++dg) {
      short4v va = *(const short4v*)(vr + dg * 2048);
      o[dg] = mfma16k16(va, pk.s4, o[dg]);
    }
  };

  // prologue: tile0 -> buf0, (tile1 -> buf1 if it exists)
#pragma unroll
  for (int j = 0; j < 4; ++j) { async16(gsrc[j], ldst[j]); gsrc[j] += step[j]; }
  if (nt > 1) {
#pragma unroll
    for (int j = 0; j < 4; ++j) { async16(gsrc[j], ldst[j] + 4096); gsrc[j] += step[j]; }
  }

  for (int t = 0; t < nt; ++t) {
    if (t + 1 < nt) asm volatile("s_waitcnt vmcnt(4)" ::: "memory");
    else            asm volatile("s_waitcnt vmcnt(0)" ::: "memory");
    __builtin_amdgcn_s_barrier();
    asm volatile("" ::: "memory");
    const char* Kc = (const char*)Ks + (t & 1) * 8192;
    const char* Vc = (const char*)Vs + (t & 1) * 8192;
    if (t < s) {
#pragma unroll
      for (int kg = 0; kg < 4; ++kg) body(Kc, Vc, kg, false);
    } else {
      // diagonal tile: kg > w fully masked, kg == w partially
      for (int kg = 0; kg < w; ++kg) body(Kc, Vc, kg, false);
      body(Kc, Vc, w, true);
    }
    asm volatile("" ::: "memory");
    __builtin_amdgcn_s_barrier();
    asm volatile("" ::: "memory");
    if (t + 2 < nt) {
#pragma unroll
      for (int j = 0; j < 4; ++j) {
        async16(gsrc[j], ldst[j] + (t & 1) * 4096);
        gsrc[j] += step[j];
      }
    }
  }

  // lacc[*] = rowsum for q-row lm (identical across regs/lk groups)
  float inv = 1.f / lacc[0];

  US* crow = ctx + ((size_t)(bh >> 4) * SEQ + qb + lm) * NOUTF + (bh & 15) * DHEAD;
#pragma unroll
  for (int dg = 0; dg < 4; ++dg) {
    union { short4v s4; uint32_t u[2]; } pk;
    pk.u[0] = (uint32_t)f2bf(o[dg][0] * inv) | ((uint32_t)f2bf(o[dg][1] * inv) << 16);
    pk.u[1] = (uint32_t)f2bf(o[dg][2] * inv) | ((uint32_t)f2bf(o[dg][3] * inv) << 16);
    *(short4v*)(crow + dg * 16 + lk * 4) = pk.s4;
  }
}

// ---------------- out GEMM (round-0 original, in the 181.2us best) ---------
__global__ __launch_bounds__(256) void k_gemm_out(
    const US* __restrict__ A, const US* __restrict__ Bt,
    const float* __restrict__ bias, float* __restrict__ out) {
  __shared__ US As[128 * 32];
  __shared__ US Bs[64 * 32];
  int tid = threadIdx.x;
  int wave = tid >> 6, lane = tid & 63, lm = lane & 15, lk = lane >> 4;
  int mbase = blockIdx.y * 128, nbase = blockIdx.x * 64;

  f32x4 acc[2][4];
#pragma unroll
  for (int i = 0; i < 2; ++i)
#pragma unroll
    for (int j = 0; j < 4; ++j) acc[i][j] = (f32x4){0.f, 0.f, 0.f, 0.f};

  const US* ga = A + (size_t)(mbase + (tid >> 2)) * NOUTF + (tid & 3) * 8;
  const US* gb = Bt + (size_t)(nbase + (tid >> 2)) * NOUTF + (tid & 3) * 8;
  US* la = As + tid * 8;
  US* lb = Bs + tid * 8;

  for (int kt = 0; kt < NOUTF / 32; ++kt) {
    int ko = kt * 32;
    async16(ga + ko, la);
    async16(ga + ko + (size_t)64 * NOUTF, la + 64 * 32);
    async16(gb + ko, lb);
    __syncthreads();
    short8 a[2], b[4];
#pragma unroll
    for (int i = 0; i < 2; ++i)
      a[i] = *(const short8*)(As + (wave * 32 + i * 16 + lm) * 32 + lk * 8);
#pragma unroll
    for (int j = 0; j < 4; ++j)
      b[j] = *(const short8*)(Bs + (j * 16 + lm) * 32 + lk * 8);
#pragma unroll
    for (int i = 0; i < 2; ++i)
#pragma unroll
      for (int j = 0; j < 4; ++j) acc[i][j] = mfma16(a[i], b[j], acc[i][j]);
    __syncthreads();
  }

#pragma unroll
  for (int j = 0; j < 4; ++j) {
    int col = nbase + j * 16 + lm;
    float bv = bias[col];
#pragma unroll
    for (int i = 0; i < 2; ++i)
#pragma unroll
      for (int r = 0; r < 4; ++r) {
        int row = mbase + wave * 32 + i * 16 + lk * 4 + r;
        out[(size_t)row * NOUTF + col] = acc[i][j][r] + bv;
      }
  }
}

extern "C" void kernel_launch(void* const* d_in, const int* in_sizes, int n_in,
                              void* d_out, int out_size, void* d_ws, size_t ws_size,
                              hipStream_t stream) {
  const float* y    = (const float*)d_in[0];
  const float* Wqkv = (const float*)d_in[1];
  const float* Wff  = (const float*)d_in[2];
  const float* bff  = (const float*)d_in[3];
  float* out = (float*)d_out;

  char* ws = (char*)d_ws;
  US* ybf   = (US*)(ws);                 // [0,8M)  y bf16; dead after qkv
  US* ctx   = (US*)(ws);                 // [0,8M)  reuse for ctx
  US* wqkvt = (US*)(ws + (8u << 20));    // [8,14M)
  US* wfft  = (US*)(ws + (14u << 20));   // [14,16M)
  US* qbuf  = (US*)(ws + (16u << 20));   // [16,24M)
  US* kbuf  = (US*)(ws + (24u << 20));   // [24,32M)
  US* vbuf  = (US*)(ws + (32u << 20));   // [32,40M) dead after vtrans
  US* vtbuf = (US*)(ws + (40u << 20));   // [40,48M)

  k_pre<<<dim3(8192), 256, 0, stream>>>(y, ybf, Wqkv, Wff, wqkvt, wfft);
  k_gemm_qkv<<<dim3(N3 / 128, MTOT / 128), 256, 0, stream>>>(ybf, wqkvt, qbuf, kbuf, vbuf);
  k_vtrans<<<dim3(DHEAD / 32, SEQ / 32, BATCH * NHEADS), dim3(32, 8), 0, stream>>>(vbuf, vtbuf);
  k_attn<<<dim3(1024), 256, 0, stream>>>(qbuf, kbuf, vtbuf, ctx);
  k_gemm_out<<<dim3(NOUTF / 64, MTOT / 128), 256, 0, stream>>>(ctx, wfft, bff, out);
}